// Round 8
// baseline (5418.411 us; speedup 1.0000x reference)
//
#include <hip/hip_runtime.h>
#include <hip/hip_bf16.h>
#include <math.h>

// ---------------------------------------------------------------------------
// Fused linear cross-entropy:  hidden(2047x2048) @ W^T(151936x2048) -> LSE - tgt
// Round 8: MX-FP8 (verified numerics) with register-pressure restructure:
// 8 waves / 128x128 tile (512 thr, 2m x 4n), per-wave 64x32 -> acc 32 regs
// (was 64). Total liveness ~110 << 170 cap of __launch_bounds__(512,3).
// Rounds 6/7 spilled acc every K-step (8.9-10.6 GB scratch traffic).
// ---------------------------------------------------------------------------

#define V_SIZE   151936
#define H_SIZE   2048
#define M_ROWS   2048      // 2047 real rows + 1 zero pad row
#define M_REAL   2047
#define NB_CNT   1187      // 151936 / 128 exact
#define BM 128
#define BN 128
#define BKB 128            // K-bytes per step (fp8)
#define KSTEPS (H_SIZE / BKB)    // 16
#define NBLK (16 * NB_CNT)       // 18992 = 8 * 2374
#define IGNORE_INDEX (-100)

typedef int   i32x4  __attribute__((ext_vector_type(4)));
typedef int   i32x8  __attribute__((ext_vector_type(8)));
typedef float floatx4 __attribute__((ext_vector_type(4)));

#define SCALE_ONE   0x7F7F7F7FU   // E8M0 127 -> 2^0
#define SCALE_W     0x79797979U   // E8M0 121 -> 2^-6 (undo W*64)

__device__ __forceinline__ void gload16(const void* g, void* l) {
    __builtin_amdgcn_global_load_lds(
        (const __attribute__((address_space(1))) unsigned int*)g,
        (__attribute__((address_space(3))) unsigned int*)l, 16, 0, 0);
}

// ---- conversion kernels: fp32 -> fp8 e4m3 (OCP) via v_cvt_pk_fp8_f32 ------

__global__ void cvt_w_fp8(const float4* __restrict__ in,
                          unsigned* __restrict__ out, long n4) {
    long i = (long)blockIdx.x * blockDim.x + threadIdx.x;
    long stride = (long)gridDim.x * blockDim.x;
    for (; i < n4; i += stride) {
        float4 v = in[i];
        int r = __builtin_amdgcn_cvt_pk_fp8_f32(v.x * 64.f, v.y * 64.f, 0, false);
        r = __builtin_amdgcn_cvt_pk_fp8_f32(v.z * 64.f, v.w * 64.f, r, true);
        out[i] = (unsigned)r;
    }
}

__global__ void cvt_h_fp8(const float4* __restrict__ in,
                          unsigned* __restrict__ out) {
    const long n4 = (long)M_ROWS * H_SIZE / 4;       // 1,048,576
    const long valid4 = (long)M_REAL * H_SIZE / 4;   // 1,048,064
    long i = (long)blockIdx.x * blockDim.x + threadIdx.x;
    long stride = (long)gridDim.x * blockDim.x;
    for (; i < n4; i += stride) {
        unsigned o = 0;
        if (i < valid4) {
            float4 v = in[i];
            int r = __builtin_amdgcn_cvt_pk_fp8_f32(v.x, v.y, 0, false);
            r = __builtin_amdgcn_cvt_pk_fp8_f32(v.z, v.w, r, true);
            o = (unsigned)r;
        }
        out[i] = o;
    }
}

// ---- main GEMM + per-tile online-LSE epilogue ------------------------------
// 512 threads = 8 waves (wm 0..1 -> 64-row half, wn 0..3 -> 32-col slab).
// Per-wave: acc[4][2] (32 regs), af[4] (32), bfv[2] (16).
// 2-barrier K-loop: gload(4/thread) -> sync -> ds_read frags + 8 MFMA -> sync.

__global__ __launch_bounds__(512, 3) void gemm_lse(
    const unsigned char* __restrict__ hq,     // [2048][2048] fp8
    const unsigned char* __restrict__ wq,     // [151936][2048] fp8 (x64)
    float* __restrict__ pmax,                 // [1187][2048]
    float* __restrict__ psum) {               // [1187][2048]
    __shared__ unsigned char ldsA[BM * BKB];  // [128 rows][8 chunks of 16B]
    __shared__ unsigned char ldsB[BN * BKB];
    __shared__ float eM[BM][4];
    __shared__ float eS[BM][4];

    const int t    = threadIdx.x;
    const int lane = t & 63;
    const int w    = t >> 6;
    const int wm   = w >> 2;          // 0..1 -> 64-row half
    const int wn   = w & 3;           // 0..3 -> 32-col slab

    // T1: XCD-bijective remap (18992 = 8*2374), m fast for W-slab L2 reuse
    const int b    = blockIdx.x;
    const int lin  = (b & 7) * (NBLK / 8) + (b >> 3);
    const int mb   = lin & 15;
    const int nb   = lin >> 4;
    const int m0   = mb * BM;
    const int n0   = nb * BN;

    // staging: thread t -> row t>>3 (0..63, +64 on 2nd issue), phys chunk t&7;
    // global logical chunk pre-swizzled (T2, rule 21): (t&7)^(row&7).
    const int srow   = t >> 3;
    const int schunk = (t & 7) ^ (srow & 7);
    const unsigned char* gA = hq + (size_t)(m0 + srow) * H_SIZE + schunk * 16;
    const unsigned char* gB = wq + (size_t)(n0 + srow) * H_SIZE + schunk * 16;
    unsigned char* la = ldsA + t * 16;
    unsigned char* lb = ldsB + t * 16;

    floatx4 zero4 = {0.f, 0.f, 0.f, 0.f};
    floatx4 acc[4][2];
#pragma unroll
    for (int i = 0; i < 4; ++i)
#pragma unroll
        for (int j = 0; j < 2; ++j) acc[i][j] = zero4;

    const int fr = lane & 15;       // fragment row/col within 16
    const int fq = lane >> 4;       // 0..3 -> 32-byte k-group
    const int sw = fr & 7;          // read-side swizzle (row&7 == fr&7)

    for (int kt = 0; kt < KSTEPS; ++kt) {
        const int kof = kt * BKB;
        gload16(gA + kof, la);
        gload16(gA + (size_t)64 * H_SIZE + kof, la + 8192);
        gload16(gB + kof, lb);
        gload16(gB + (size_t)64 * H_SIZE + kof, lb + 8192);
        __syncthreads();

        // A fragments: 32 k-bytes = two XOR-swizzled 16B chunks (2fq, 2fq+1)
        i32x8 af[4];
#pragma unroll
        for (int i = 0; i < 4; ++i) {
            const unsigned char* p = ldsA + (size_t)(wm * 64 + i * 16 + fr) * BKB;
            i32x4 lo = *(const i32x4*)(p + ((2 * fq) ^ sw) * 16);
            i32x4 hi = *(const i32x4*)(p + ((2 * fq + 1) ^ sw) * 16);
            i32x8 a;
            a[0] = lo[0]; a[1] = lo[1]; a[2] = lo[2]; a[3] = lo[3];
            a[4] = hi[0]; a[5] = hi[1]; a[6] = hi[2]; a[7] = hi[3];
            af[i] = a;
        }
        i32x8 bfv[2];
#pragma unroll
        for (int j = 0; j < 2; ++j) {
            const unsigned char* p = ldsB + (size_t)(wn * 32 + j * 16 + fr) * BKB;
            i32x4 lo = *(const i32x4*)(p + ((2 * fq) ^ sw) * 16);
            i32x4 hi = *(const i32x4*)(p + ((2 * fq + 1) ^ sw) * 16);
            i32x8 bb;
            bb[0] = lo[0]; bb[1] = lo[1]; bb[2] = lo[2]; bb[3] = lo[3];
            bb[4] = hi[0]; bb[5] = hi[1]; bb[6] = hi[2]; bb[7] = hi[3];
            bfv[j] = bb;
        }
#pragma unroll
        for (int j = 0; j < 2; ++j)
#pragma unroll
            for (int i = 0; i < 4; ++i)
                acc[i][j] = __builtin_amdgcn_mfma_scale_f32_16x16x128_f8f6f4(
                    af[i], bfv[j], acc[i][j],
                    0, 0,                      // cbsz=FP8(e4m3), blgp=FP8(e4m3)
                    0, (int)SCALE_ONE,         // A scale: 2^0
                    0, (int)SCALE_W);          // B scale: 2^-6
        __syncthreads();
    }

    // epilogue: per-row max + sum(exp) over this wave's 32 vocab columns.
    // C/D layout (shape-determined): col = lane&15, row = (lane>>4)*4 + reg.
#pragma unroll
    for (int i = 0; i < 4; ++i) {
#pragma unroll
        for (int r = 0; r < 4; ++r) {
            float v = fmaxf(acc[i][0][r], acc[i][1][r]);
            for (int off = 1; off < 16; off <<= 1)
                v = fmaxf(v, __shfl_xor(v, off, 64));
            float s = expf(acc[i][0][r] - v) + expf(acc[i][1][r] - v);
            for (int off = 1; off < 16; off <<= 1)
                s += __shfl_xor(s, off, 64);
            if (fr == 0) {
                int row = wm * 64 + i * 16 + fq * 4 + r;
                eM[row][wn] = v;
                eS[row][wn] = s;
            }
        }
    }
    __syncthreads();
    if (t < BM) {
        float Mx = eM[t][0];
        for (int i = 1; i < 4; ++i) Mx = fmaxf(Mx, eM[t][i]);
        float Sx = 0.f;
        for (int i = 0; i < 4; ++i)
            Sx += eS[t][i] * expf(eM[t][i] - Mx);
        size_t grow = (size_t)m0 + t;
        pmax[(size_t)nb * M_ROWS + grow] = Mx;
        psum[(size_t)nb * M_ROWS + grow] = Sx;
    }
}

// ---- per-row reduction: combine partials + exact fp32 target dot -----------

__global__ void zero_acc(float* a) {
    if (threadIdx.x < 2) a[threadIdx.x] = 0.f;
}

__global__ __launch_bounds__(256) void reduce_rows(
    const float* __restrict__ hid,
    const int* __restrict__ labels,
    const float* __restrict__ wt,
    const float* __restrict__ pmax,
    const float* __restrict__ psum,
    float* __restrict__ accum) {
    const int m = blockIdx.x;           // 0..2046
    const int t = threadIdx.x;
    const int lbl = labels[m + 1];
    const bool valid = (lbl != IGNORE_INDEX);

    float dot = 0.f;
    if (valid) {
        int li = lbl < 0 ? 0 : lbl;
        const float4* hr = (const float4*)(hid + (size_t)m * H_SIZE);
        const float4* wr = (const float4*)(wt + (size_t)li * H_SIZE);
#pragma unroll
        for (int i = 0; i < 2; ++i) {
            float4 a = hr[t + i * 256];
            float4 b = wr[t + i * 256];
            dot += a.x * b.x + a.y * b.y + a.z * b.z + a.w * b.w;
        }
    }

    float M = -INFINITY, S = 0.f;
    for (int nbi = t; nbi < NB_CNT; nbi += 256) {
        float m2 = pmax[(size_t)nbi * M_ROWS + m];
        float s2 = psum[(size_t)nbi * M_ROWS + m];
        if (m2 > M) { S = S * expf(M - m2) + s2; M = m2; }
        else        { S += s2 * expf(m2 - M); }
    }
    for (int off = 1; off < 64; off <<= 1) {
        float M2 = __shfl_xor(M, off, 64);
        float S2 = __shfl_xor(S, off, 64);
        float nm = fmaxf(M, M2);
        S = S * expf(M - nm) + S2 * expf(M2 - nm);
        M = nm;
        dot += __shfl_xor(dot, off, 64);
    }
    __shared__ float rM[4], rS[4], rD[4];
    const int wv = t >> 6, lane = t & 63;
    if (lane == 0) { rM[wv] = M; rS[wv] = S; rD[wv] = dot; }
    __syncthreads();
    if (t == 0) {
        float Mx = rM[0], Sx = rS[0], D = rD[0];
        for (int i = 1; i < 4; ++i) {
            float nm = fmaxf(Mx, rM[i]);
            Sx = Sx * expf(Mx - nm) + rS[i] * expf(rM[i] - nm);
            Mx = nm;
            D += rD[i];
        }
        if (valid) {
            atomicAdd(&accum[0], (Mx + logf(Sx)) - D);
            atomicAdd(&accum[1], 1.0f);
        }
    }
}

__global__ void finalize(const float* __restrict__ accum, float* __restrict__ out) {
    out[0] = accum[0] / accum[1];
}

__global__ void sentinel(float* out) { out[0] = -12345.0f; }

// ---------------------------------------------------------------------------

extern "C" void kernel_launch(void* const* d_in, const int* in_sizes, int n_in,
                              void* d_out, int out_size, void* d_ws, size_t ws_size,
                              hipStream_t stream) {
    const float* hid    = (const float*)d_in[0];
    const int*   labels = (const int*)d_in[1];
    const float* wt     = (const float*)d_in[2];
    float* out = (float*)d_out;

    const size_t wq_bytes   = (size_t)V_SIZE * H_SIZE;         // 311,166,976
    const size_t hq_bytes   = (size_t)M_ROWS * H_SIZE;         //   4,194,304
    const size_t part_bytes = (size_t)NB_CNT * M_ROWS * 4;     //   9,723,904
    const size_t off_wq   = 0;
    const size_t off_hq   = off_wq + wq_bytes;
    const size_t off_pmax = off_hq + hq_bytes;
    const size_t off_psum = off_pmax + part_bytes;
    const size_t off_acc  = off_psum + part_bytes;
    const size_t need     = off_acc + 16;

    if (ws_size < need) {   // diagnosable failure: out = -12345
        sentinel<<<1, 1, 0, stream>>>(out);
        return;
    }

    unsigned char* wq = (unsigned char*)((char*)d_ws + off_wq);
    unsigned char* hq = (unsigned char*)((char*)d_ws + off_hq);
    float* pmax = (float*)((char*)d_ws + off_pmax);
    float* psum = (float*)((char*)d_ws + off_psum);
    float* accum = (float*)((char*)d_ws + off_acc);

    zero_acc<<<1, 64, 0, stream>>>(accum);

    long w4 = (long)V_SIZE * H_SIZE / 4;
    cvt_w_fp8<<<2048, 256, 0, stream>>>((const float4*)wt, (unsigned*)wq, w4);
    cvt_h_fp8<<<1024, 256, 0, stream>>>((const float4*)hid, (unsigned*)hq);

    gemm_lse<<<NBLK, 512, 0, stream>>>(hq, wq, pmax, psum);

    reduce_rows<<<M_REAL, 256, 0, stream>>>(hid, labels, wt, pmax, psum, accum);
    finalize<<<1, 1, 0, stream>>>(accum, out);
}

// Round 9
// 4067.384 us; speedup vs baseline: 1.3322x; 1.3322x over previous
//
#include <hip/hip_runtime.h>
#include <hip/hip_bf16.h>
#include <math.h>

// ---------------------------------------------------------------------------
// Fused linear cross-entropy:  hidden(2047x2048) @ W^T(151936x2048) -> LSE - tgt
// Round 9: round 8 (MX-FP8, 8 waves, acc[4][2]) with the REAL register fix:
// __launch_bounds__(512, 1). Measured allocator behavior: arg k -> cap
// ~512/(2k) regs ((256,4)->64, (256,3)/(512,3)->84). All prior MX rounds were
// capped at 64-84 regs vs ~110-156 demand -> forced spill (9-10 GB scratch).
// ---------------------------------------------------------------------------

#define V_SIZE   151936
#define H_SIZE   2048
#define M_ROWS   2048      // 2047 real rows + 1 zero pad row
#define M_REAL   2047
#define NB_CNT   1187      // 151936 / 128 exact
#define BM 128
#define BN 128
#define BKB 128            // K-bytes per step (fp8)
#define KSTEPS (H_SIZE / BKB)    // 16
#define NBLK (16 * NB_CNT)       // 18992 = 8 * 2374
#define IGNORE_INDEX (-100)

typedef int   i32x4  __attribute__((ext_vector_type(4)));
typedef int   i32x8  __attribute__((ext_vector_type(8)));
typedef float floatx4 __attribute__((ext_vector_type(4)));

#define SCALE_ONE   0x7F7F7F7FU   // E8M0 127 -> 2^0
#define SCALE_W     0x79797979U   // E8M0 121 -> 2^-6 (undo W*64)

__device__ __forceinline__ void gload16(const void* g, void* l) {
    __builtin_amdgcn_global_load_lds(
        (const __attribute__((address_space(1))) unsigned int*)g,
        (__attribute__((address_space(3))) unsigned int*)l, 16, 0, 0);
}

// ---- conversion kernels: fp32 -> fp8 e4m3 (OCP) via v_cvt_pk_fp8_f32 ------

__global__ void cvt_w_fp8(const float4* __restrict__ in,
                          unsigned* __restrict__ out, long n4) {
    long i = (long)blockIdx.x * blockDim.x + threadIdx.x;
    long stride = (long)gridDim.x * blockDim.x;
    for (; i < n4; i += stride) {
        float4 v = in[i];
        int r = __builtin_amdgcn_cvt_pk_fp8_f32(v.x * 64.f, v.y * 64.f, 0, false);
        r = __builtin_amdgcn_cvt_pk_fp8_f32(v.z * 64.f, v.w * 64.f, r, true);
        out[i] = (unsigned)r;
    }
}

__global__ void cvt_h_fp8(const float4* __restrict__ in,
                          unsigned* __restrict__ out) {
    const long n4 = (long)M_ROWS * H_SIZE / 4;       // 1,048,576
    const long valid4 = (long)M_REAL * H_SIZE / 4;   // 1,048,064
    long i = (long)blockIdx.x * blockDim.x + threadIdx.x;
    long stride = (long)gridDim.x * blockDim.x;
    for (; i < n4; i += stride) {
        unsigned o = 0;
        if (i < valid4) {
            float4 v = in[i];
            int r = __builtin_amdgcn_cvt_pk_fp8_f32(v.x, v.y, 0, false);
            r = __builtin_amdgcn_cvt_pk_fp8_f32(v.z, v.w, r, true);
            o = (unsigned)r;
        }
        out[i] = o;
    }
}

// ---- main GEMM + per-tile online-LSE epilogue ------------------------------
// 512 threads = 8 waves (wm 0..1 -> 64-row half, wn 0..3 -> 32-col slab).
// Per-wave: acc[4][2] (32 regs), af[4] (32), bfv[2] (16).
// 2-barrier K-loop: gload(4/thread) -> sync -> ds_read frags + 8 MFMA -> sync.

__global__ __launch_bounds__(512, 1) void gemm_lse(
    const unsigned char* __restrict__ hq,     // [2048][2048] fp8
    const unsigned char* __restrict__ wq,     // [151936][2048] fp8 (x64)
    float* __restrict__ pmax,                 // [1187][2048]
    float* __restrict__ psum) {               // [1187][2048]
    __shared__ unsigned char ldsA[BM * BKB];  // [128 rows][8 chunks of 16B]
    __shared__ unsigned char ldsB[BN * BKB];
    __shared__ float eM[BM][4];
    __shared__ float eS[BM][4];

    const int t    = threadIdx.x;
    const int lane = t & 63;
    const int w    = t >> 6;
    const int wm   = w >> 2;          // 0..1 -> 64-row half
    const int wn   = w & 3;           // 0..3 -> 32-col slab

    // T1: XCD-bijective remap (18992 = 8*2374), m fast for W-slab L2 reuse
    const int b    = blockIdx.x;
    const int lin  = (b & 7) * (NBLK / 8) + (b >> 3);
    const int mb   = lin & 15;
    const int nb   = lin >> 4;
    const int m0   = mb * BM;
    const int n0   = nb * BN;

    // staging: thread t -> row t>>3 (0..63, +64 on 2nd issue), phys chunk t&7;
    // global logical chunk pre-swizzled (T2, rule 21): (t&7)^(row&7).
    const int srow   = t >> 3;
    const int schunk = (t & 7) ^ (srow & 7);
    const unsigned char* gA = hq + (size_t)(m0 + srow) * H_SIZE + schunk * 16;
    const unsigned char* gB = wq + (size_t)(n0 + srow) * H_SIZE + schunk * 16;
    unsigned char* la = ldsA + t * 16;
    unsigned char* lb = ldsB + t * 16;

    floatx4 zero4 = {0.f, 0.f, 0.f, 0.f};
    floatx4 acc[4][2];
#pragma unroll
    for (int i = 0; i < 4; ++i)
#pragma unroll
        for (int j = 0; j < 2; ++j) acc[i][j] = zero4;

    const int fr = lane & 15;       // fragment row/col within 16
    const int fq = lane >> 4;       // 0..3 -> 32-byte k-group
    const int sw = fr & 7;          // read-side swizzle (row&7 == fr&7)

    for (int kt = 0; kt < KSTEPS; ++kt) {
        const int kof = kt * BKB;
        gload16(gA + kof, la);
        gload16(gA + (size_t)64 * H_SIZE + kof, la + 8192);
        gload16(gB + kof, lb);
        gload16(gB + (size_t)64 * H_SIZE + kof, lb + 8192);
        __syncthreads();

        // A fragments: 32 k-bytes = two XOR-swizzled 16B chunks (2fq, 2fq+1)
        i32x8 af[4];
#pragma unroll
        for (int i = 0; i < 4; ++i) {
            const unsigned char* p = ldsA + (size_t)(wm * 64 + i * 16 + fr) * BKB;
            i32x4 lo = *(const i32x4*)(p + ((2 * fq) ^ sw) * 16);
            i32x4 hi = *(const i32x4*)(p + ((2 * fq + 1) ^ sw) * 16);
            i32x8 a;
            a[0] = lo[0]; a[1] = lo[1]; a[2] = lo[2]; a[3] = lo[3];
            a[4] = hi[0]; a[5] = hi[1]; a[6] = hi[2]; a[7] = hi[3];
            af[i] = a;
        }
        i32x8 bfv[2];
#pragma unroll
        for (int j = 0; j < 2; ++j) {
            const unsigned char* p = ldsB + (size_t)(wn * 32 + j * 16 + fr) * BKB;
            i32x4 lo = *(const i32x4*)(p + ((2 * fq) ^ sw) * 16);
            i32x4 hi = *(const i32x4*)(p + ((2 * fq + 1) ^ sw) * 16);
            i32x8 bb;
            bb[0] = lo[0]; bb[1] = lo[1]; bb[2] = lo[2]; bb[3] = lo[3];
            bb[4] = hi[0]; bb[5] = hi[1]; bb[6] = hi[2]; bb[7] = hi[3];
            bfv[j] = bb;
        }
#pragma unroll
        for (int j = 0; j < 2; ++j)
#pragma unroll
            for (int i = 0; i < 4; ++i)
                acc[i][j] = __builtin_amdgcn_mfma_scale_f32_16x16x128_f8f6f4(
                    af[i], bfv[j], acc[i][j],
                    0, 0,                      // cbsz=FP8(e4m3), blgp=FP8(e4m3)
                    0, (int)SCALE_ONE,         // A scale: 2^0
                    0, (int)SCALE_W);          // B scale: 2^-6
        __syncthreads();
    }

    // epilogue: per-row max + sum(exp) over this wave's 32 vocab columns.
    // C/D layout (shape-determined): col = lane&15, row = (lane>>4)*4 + reg.
#pragma unroll
    for (int i = 0; i < 4; ++i) {
#pragma unroll
        for (int r = 0; r < 4; ++r) {
            float v = fmaxf(acc[i][0][r], acc[i][1][r]);
            for (int off = 1; off < 16; off <<= 1)
                v = fmaxf(v, __shfl_xor(v, off, 64));
            float s = expf(acc[i][0][r] - v) + expf(acc[i][1][r] - v);
            for (int off = 1; off < 16; off <<= 1)
                s += __shfl_xor(s, off, 64);
            if (fr == 0) {
                int row = wm * 64 + i * 16 + fq * 4 + r;
                eM[row][wn] = v;
                eS[row][wn] = s;
            }
        }
    }
    __syncthreads();
    if (t < BM) {
        float Mx = eM[t][0];
        for (int i = 1; i < 4; ++i) Mx = fmaxf(Mx, eM[t][i]);
        float Sx = 0.f;
        for (int i = 0; i < 4; ++i)
            Sx += eS[t][i] * expf(eM[t][i] - Mx);
        size_t grow = (size_t)m0 + t;
        pmax[(size_t)nb * M_ROWS + grow] = Mx;
        psum[(size_t)nb * M_ROWS + grow] = Sx;
    }
}

// ---- per-row reduction: combine partials + exact fp32 target dot -----------

__global__ void zero_acc(float* a) {
    if (threadIdx.x < 2) a[threadIdx.x] = 0.f;
}

__global__ __launch_bounds__(256) void reduce_rows(
    const float* __restrict__ hid,
    const int* __restrict__ labels,
    const float* __restrict__ wt,
    const float* __restrict__ pmax,
    const float* __restrict__ psum,
    float* __restrict__ accum) {
    const int m = blockIdx.x;           // 0..2046
    const int t = threadIdx.x;
    const int lbl = labels[m + 1];
    const bool valid = (lbl != IGNORE_INDEX);

    float dot = 0.f;
    if (valid) {
        int li = lbl < 0 ? 0 : lbl;
        const float4* hr = (const float4*)(hid + (size_t)m * H_SIZE);
        const float4* wr = (const float4*)(wt + (size_t)li * H_SIZE);
#pragma unroll
        for (int i = 0; i < 2; ++i) {
            float4 a = hr[t + i * 256];
            float4 b = wr[t + i * 256];
            dot += a.x * b.x + a.y * b.y + a.z * b.z + a.w * b.w;
        }
    }

    float M = -INFINITY, S = 0.f;
    for (int nbi = t; nbi < NB_CNT; nbi += 256) {
        float m2 = pmax[(size_t)nbi * M_ROWS + m];
        float s2 = psum[(size_t)nbi * M_ROWS + m];
        if (m2 > M) { S = S * expf(M - m2) + s2; M = m2; }
        else        { S += s2 * expf(m2 - M); }
    }
    for (int off = 1; off < 64; off <<= 1) {
        float M2 = __shfl_xor(M, off, 64);
        float S2 = __shfl_xor(S, off, 64);
        float nm = fmaxf(M, M2);
        S = S * expf(M - nm) + S2 * expf(M2 - nm);
        M = nm;
        dot += __shfl_xor(dot, off, 64);
    }
    __shared__ float rM[4], rS[4], rD[4];
    const int wv = t >> 6, lane = t & 63;
    if (lane == 0) { rM[wv] = M; rS[wv] = S; rD[wv] = dot; }
    __syncthreads();
    if (t == 0) {
        float Mx = rM[0], Sx = rS[0], D = rD[0];
        for (int i = 1; i < 4; ++i) {
            float nm = fmaxf(Mx, rM[i]);
            Sx = Sx * expf(Mx - nm) + rS[i] * expf(rM[i] - nm);
            Mx = nm;
            D += rD[i];
        }
        if (valid) {
            atomicAdd(&accum[0], (Mx + logf(Sx)) - D);
            atomicAdd(&accum[1], 1.0f);
        }
    }
}

__global__ void finalize(const float* __restrict__ accum, float* __restrict__ out) {
    out[0] = accum[0] / accum[1];
}

__global__ void sentinel(float* out) { out[0] = -12345.0f; }

// ---------------------------------------------------------------------------

extern "C" void kernel_launch(void* const* d_in, const int* in_sizes, int n_in,
                              void* d_out, int out_size, void* d_ws, size_t ws_size,
                              hipStream_t stream) {
    const float* hid    = (const float*)d_in[0];
    const int*   labels = (const int*)d_in[1];
    const float* wt     = (const float*)d_in[2];
    float* out = (float*)d_out;

    const size_t wq_bytes   = (size_t)V_SIZE * H_SIZE;         // 311,166,976
    const size_t hq_bytes   = (size_t)M_ROWS * H_SIZE;         //   4,194,304
    const size_t part_bytes = (size_t)NB_CNT * M_ROWS * 4;     //   9,723,904
    const size_t off_wq   = 0;
    const size_t off_hq   = off_wq + wq_bytes;
    const size_t off_pmax = off_hq + hq_bytes;
    const size_t off_psum = off_pmax + part_bytes;
    const size_t off_acc  = off_psum + part_bytes;
    const size_t need     = off_acc + 16;

    if (ws_size < need) {   // diagnosable failure: out = -12345
        sentinel<<<1, 1, 0, stream>>>(out);
        return;
    }

    unsigned char* wq = (unsigned char*)((char*)d_ws + off_wq);
    unsigned char* hq = (unsigned char*)((char*)d_ws + off_hq);
    float* pmax = (float*)((char*)d_ws + off_pmax);
    float* psum = (float*)((char*)d_ws + off_psum);
    float* accum = (float*)((char*)d_ws + off_acc);

    zero_acc<<<1, 64, 0, stream>>>(accum);

    long w4 = (long)V_SIZE * H_SIZE / 4;
    cvt_w_fp8<<<2048, 256, 0, stream>>>((const float4*)wt, (unsigned*)wq, w4);
    cvt_h_fp8<<<1024, 256, 0, stream>>>((const float4*)hid, (unsigned*)hq);

    gemm_lse<<<NBLK, 512, 0, stream>>>(hq, wq, pmax, psum);

    reduce_rows<<<M_REAL, 256, 0, stream>>>(hid, labels, wt, pmax, psum, accum);
    finalize<<<1, 1, 0, stream>>>(accum, out);
}

// Round 10
// 2597.009 us; speedup vs baseline: 2.0864x; 1.5662x over previous
//
#include <hip/hip_runtime.h>
#include <hip/hip_bf16.h>
#include <math.h>

// ---------------------------------------------------------------------------
// Fused linear cross-entropy:  hidden(2047x2048) @ W^T(151936x2048) -> LSE - tgt
// Round 10: MX-FP8 with CONTIGUOUS 32B fragment loads. T2 swizzle moved to
// 32B granularity (phys32 = log32 ^ (row&3)) so each MFMA operand is one
// i32x8 load (2 adjacent ds_read_b128) -> no element-wise tuple construction,
// ~50 fewer live arch regs (rounds 6-9 spilled on exactly this).
// 256 thr, 2x2 waves, 64x64/wave (reread 2+2), __launch_bounds__(256,1).
// ---------------------------------------------------------------------------

#define V_SIZE   151936
#define H_SIZE   2048
#define M_ROWS   2048      // 2047 real rows + 1 zero pad row
#define M_REAL   2047
#define NB_CNT   1187      // 151936 / 128 exact
#define BM 128
#define BN 128
#define BKB 128            // K-bytes per step (fp8)
#define KSTEPS (H_SIZE / BKB)    // 16
#define NBLK (16 * NB_CNT)       // 18992 = 8 * 2374
#define IGNORE_INDEX (-100)

typedef int   i32x8  __attribute__((ext_vector_type(8)));
typedef float floatx4 __attribute__((ext_vector_type(4)));

#define SCALE_ONE   0x7F7F7F7FU   // E8M0 127 -> 2^0
#define SCALE_W     0x79797979U   // E8M0 121 -> 2^-6 (undo W*64)

__device__ __forceinline__ void gload16(const void* g, void* l) {
    __builtin_amdgcn_global_load_lds(
        (const __attribute__((address_space(1))) unsigned int*)g,
        (__attribute__((address_space(3))) unsigned int*)l, 16, 0, 0);
}

// ---- conversion kernels: fp32 -> fp8 e4m3 (OCP) via v_cvt_pk_fp8_f32 ------

__global__ void cvt_w_fp8(const float4* __restrict__ in,
                          unsigned* __restrict__ out, long n4) {
    long i = (long)blockIdx.x * blockDim.x + threadIdx.x;
    long stride = (long)gridDim.x * blockDim.x;
    for (; i < n4; i += stride) {
        float4 v = in[i];
        int r = __builtin_amdgcn_cvt_pk_fp8_f32(v.x * 64.f, v.y * 64.f, 0, false);
        r = __builtin_amdgcn_cvt_pk_fp8_f32(v.z * 64.f, v.w * 64.f, r, true);
        out[i] = (unsigned)r;
    }
}

__global__ void cvt_h_fp8(const float4* __restrict__ in,
                          unsigned* __restrict__ out) {
    const long n4 = (long)M_ROWS * H_SIZE / 4;       // 1,048,576
    const long valid4 = (long)M_REAL * H_SIZE / 4;   // 1,048,064
    long i = (long)blockIdx.x * blockDim.x + threadIdx.x;
    long stride = (long)gridDim.x * blockDim.x;
    for (; i < n4; i += stride) {
        unsigned o = 0;
        if (i < valid4) {
            float4 v = in[i];
            int r = __builtin_amdgcn_cvt_pk_fp8_f32(v.x, v.y, 0, false);
            r = __builtin_amdgcn_cvt_pk_fp8_f32(v.z, v.w, r, true);
            o = (unsigned)r;
        }
        out[i] = o;
    }
}

// ---- main GEMM + per-tile online-LSE epilogue ------------------------------
// 256 threads = 4 waves (2m x 2n), per-wave 64x64 output = acc[4][4].
// LDS rows are 128B = 4x 32B chunks; phys chunk p holds logical p^(row&3).
// 2-barrier K-loop: 8 gload16/thread -> sync -> 4+4 i32x8 reads + 16 MFMA
// (K=128) -> sync.

__global__ __launch_bounds__(256, 1) void gemm_lse(
    const unsigned char* __restrict__ hq,     // [2048][2048] fp8
    const unsigned char* __restrict__ wq,     // [151936][2048] fp8 (x64)
    float* __restrict__ pmax,                 // [1187][2048]
    float* __restrict__ psum) {               // [1187][2048]
    __shared__ unsigned char ldsA[BM * BKB];
    __shared__ unsigned char ldsB[BN * BKB];
    __shared__ float eM[BM][2];
    __shared__ float eS[BM][2];

    const int t    = threadIdx.x;
    const int lane = t & 63;
    const int w    = t >> 6;
    const int wm   = w >> 1;          // 0..1 -> 64-row half
    const int wn   = w & 1;           // 0..1 -> 64-col half

    // T1: XCD-bijective remap (18992 = 8*2374), m fast for W-slab L2 reuse
    const int b    = blockIdx.x;
    const int lin  = (b & 7) * (NBLK / 8) + (b >> 3);
    const int mb   = lin & 15;
    const int nb   = lin >> 4;
    const int m0   = mb * BM;
    const int n0   = nb * BN;

    // staging: thread t -> dest byte t*16 (wave-linear), i.e. row t>>3,
    // phys 32B chunk (t>>1)&3, half t&1. Global source pre-swizzled:
    // logical32 = phys32 ^ (row&3)  (rule 21; +32-row issues keep row&3).
    const int srow = t >> 3;
    const int soff = ((((((t >> 1) & 3) ^ (srow & 3)) << 1) | (t & 1))) * 16;
    const unsigned char* gA = hq + (size_t)(m0 + srow) * H_SIZE + soff;
    const unsigned char* gB = wq + (size_t)(n0 + srow) * H_SIZE + soff;
    unsigned char* la = ldsA + t * 16;
    unsigned char* lb = ldsB + t * 16;

    floatx4 zero4 = {0.f, 0.f, 0.f, 0.f};
    floatx4 acc[4][4];
#pragma unroll
    for (int i = 0; i < 4; ++i)
#pragma unroll
        for (int j = 0; j < 4; ++j) acc[i][j] = zero4;

    const int fr = lane & 15;       // fragment row/col within 16
    const int fq = lane >> 4;       // 0..3 -> which 32B k-chunk
    const int ksw = (fq ^ (fr & 3)) << 5;   // swizzled physical 32B chunk

    for (int kt = 0; kt < KSTEPS; ++kt) {
        const int kof = kt * BKB;
#pragma unroll
        for (int i = 0; i < 4; ++i) {
            gload16(gA + (size_t)i * 32 * H_SIZE + kof, la + i * 4096);
            gload16(gB + (size_t)i * 32 * H_SIZE + kof, lb + i * 4096);
        }
        __syncthreads();

        i32x8 af[4];
#pragma unroll
        for (int i = 0; i < 4; ++i)
            af[i] = *(const i32x8*)(ldsA
                + (size_t)(wm * 64 + i * 16 + fr) * BKB + ksw);
#pragma unroll
        for (int j = 0; j < 4; ++j) {
            i32x8 bf = *(const i32x8*)(ldsB
                + (size_t)(wn * 64 + j * 16 + fr) * BKB + ksw);
#pragma unroll
            for (int i = 0; i < 4; ++i)
                acc[i][j] = __builtin_amdgcn_mfma_scale_f32_16x16x128_f8f6f4(
                    af[i], bf, acc[i][j],
                    0, 0,                      // cbsz=FP8(e4m3), blgp=FP8(e4m3)
                    0, (int)SCALE_ONE,         // A scale: 2^0
                    0, (int)SCALE_W);          // B scale: 2^-6
        }
        __syncthreads();
    }

    // epilogue: per-row max + sum(exp) over this block's 128 vocab columns.
    // C/D layout (shape-determined): col = lane&15, row = (lane>>4)*4 + reg.
#pragma unroll
    for (int i = 0; i < 4; ++i) {
#pragma unroll
        for (int r = 0; r < 4; ++r) {
            float v = -INFINITY;
#pragma unroll
            for (int j = 0; j < 4; ++j) v = fmaxf(v, acc[i][j][r]);
            for (int off = 1; off < 16; off <<= 1)
                v = fmaxf(v, __shfl_xor(v, off, 64));
            float s = 0.f;
#pragma unroll
            for (int j = 0; j < 4; ++j) s += expf(acc[i][j][r] - v);
            for (int off = 1; off < 16; off <<= 1)
                s += __shfl_xor(s, off, 64);
            if (fr == 0) {
                int row = wm * 64 + i * 16 + fq * 4 + r;
                eM[row][wn] = v;
                eS[row][wn] = s;
            }
        }
    }
    __syncthreads();
    if (t < BM) {
        float ma = eM[t][0], mb2 = eM[t][1];
        float Mx = fmaxf(ma, mb2);
        float Sx = eS[t][0] * expf(ma - Mx) + eS[t][1] * expf(mb2 - Mx);
        size_t grow = (size_t)m0 + t;
        pmax[(size_t)nb * M_ROWS + grow] = Mx;
        psum[(size_t)nb * M_ROWS + grow] = Sx;
    }
}

// ---- per-row reduction: combine partials + exact fp32 target dot -----------

__global__ void zero_acc(float* a) {
    if (threadIdx.x < 2) a[threadIdx.x] = 0.f;
}

__global__ __launch_bounds__(256) void reduce_rows(
    const float* __restrict__ hid,
    const int* __restrict__ labels,
    const float* __restrict__ wt,
    const float* __restrict__ pmax,
    const float* __restrict__ psum,
    float* __restrict__ accum) {
    const int m = blockIdx.x;           // 0..2046
    const int t = threadIdx.x;
    const int lbl = labels[m + 1];
    const bool valid = (lbl != IGNORE_INDEX);

    float dot = 0.f;
    if (valid) {
        int li = lbl < 0 ? 0 : lbl;
        const float4* hr = (const float4*)(hid + (size_t)m * H_SIZE);
        const float4* wr = (const float4*)(wt + (size_t)li * H_SIZE);
#pragma unroll
        for (int i = 0; i < 2; ++i) {
            float4 a = hr[t + i * 256];
            float4 b = wr[t + i * 256];
            dot += a.x * b.x + a.y * b.y + a.z * b.z + a.w * b.w;
        }
    }

    float M = -INFINITY, S = 0.f;
    for (int nbi = t; nbi < NB_CNT; nbi += 256) {
        float m2 = pmax[(size_t)nbi * M_ROWS + m];
        float s2 = psum[(size_t)nbi * M_ROWS + m];
        if (m2 > M) { S = S * expf(M - m2) + s2; M = m2; }
        else        { S += s2 * expf(m2 - M); }
    }
    for (int off = 1; off < 64; off <<= 1) {
        float M2 = __shfl_xor(M, off, 64);
        float S2 = __shfl_xor(S, off, 64);
        float nm = fmaxf(M, M2);
        S = S * expf(M - nm) + S2 * expf(M2 - nm);
        M = nm;
        dot += __shfl_xor(dot, off, 64);
    }
    __shared__ float rM[4], rS[4], rD[4];
    const int wv = t >> 6, lane = t & 63;
    if (lane == 0) { rM[wv] = M; rS[wv] = S; rD[wv] = dot; }
    __syncthreads();
    if (t == 0) {
        float Mx = rM[0], Sx = rS[0], D = rD[0];
        for (int i = 1; i < 4; ++i) {
            float nm = fmaxf(Mx, rM[i]);
            Sx = Sx * expf(Mx - nm) + rS[i] * expf(rM[i] - nm);
            Mx = nm;
            D += rD[i];
        }
        if (valid) {
            atomicAdd(&accum[0], (Mx + logf(Sx)) - D);
            atomicAdd(&accum[1], 1.0f);
        }
    }
}

__global__ void finalize(const float* __restrict__ accum, float* __restrict__ out) {
    out[0] = accum[0] / accum[1];
}

__global__ void sentinel(float* out) { out[0] = -12345.0f; }

// ---------------------------------------------------------------------------

extern "C" void kernel_launch(void* const* d_in, const int* in_sizes, int n_in,
                              void* d_out, int out_size, void* d_ws, size_t ws_size,
                              hipStream_t stream) {
    const float* hid    = (const float*)d_in[0];
    const int*   labels = (const int*)d_in[1];
    const float* wt     = (const float*)d_in[2];
    float* out = (float*)d_out;

    const size_t wq_bytes   = (size_t)V_SIZE * H_SIZE;         // 311,166,976
    const size_t hq_bytes   = (size_t)M_ROWS * H_SIZE;         //   4,194,304
    const size_t part_bytes = (size_t)NB_CNT * M_ROWS * 4;     //   9,723,904
    const size_t off_wq   = 0;
    const size_t off_hq   = off_wq + wq_bytes;
    const size_t off_pmax = off_hq + hq_bytes;
    const size_t off_psum = off_pmax + part_bytes;
    const size_t off_acc  = off_psum + part_bytes;
    const size_t need     = off_acc + 16;

    if (ws_size < need) {   // diagnosable failure: out = -12345
        sentinel<<<1, 1, 0, stream>>>(out);
        return;
    }

    unsigned char* wq = (unsigned char*)((char*)d_ws + off_wq);
    unsigned char* hq = (unsigned char*)((char*)d_ws + off_hq);
    float* pmax = (float*)((char*)d_ws + off_pmax);
    float* psum = (float*)((char*)d_ws + off_psum);
    float* accum = (float*)((char*)d_ws + off_acc);

    zero_acc<<<1, 64, 0, stream>>>(accum);

    long w4 = (long)V_SIZE * H_SIZE / 4;
    cvt_w_fp8<<<2048, 256, 0, stream>>>((const float4*)wt, (unsigned*)wq, w4);
    cvt_h_fp8<<<1024, 256, 0, stream>>>((const float4*)hid, (unsigned*)hq);

    gemm_lse<<<NBLK, 256, 0, stream>>>(hq, wq, pmax, psum);

    reduce_rows<<<M_REAL, 256, 0, stream>>>(hid, labels, wt, pmax, psum, accum);
    finalize<<<1, 1, 0, stream>>>(accum, out);
}